// Round 8
// baseline (360.924 us; speedup 1.0000x reference)
//
#include <hip/hip_runtime.h>

typedef __attribute__((ext_vector_type(8))) short bf16x8;
typedef __attribute__((ext_vector_type(4))) float f32x4;

#define MFMA(a, b, c) __builtin_amdgcn_mfma_f32_16x16x32_bf16(a, b, c, 0, 0, 0)

__device__ __forceinline__ unsigned short f2bf(float f) {
    unsigned u = __builtin_bit_cast(unsigned, f);
    u += 0x7fffu + ((u >> 16) & 1u);
    return (unsigned short)(u >> 16);
}

// async global->LDS DMA, 16B per lane; hardware writes lane i's data at
// (wave-uniform) lds base + i*16B. gptr is per-lane.
__device__ __forceinline__ void gload16(const unsigned short* g, unsigned short* l) {
    __builtin_amdgcn_global_load_lds(
        (const __attribute__((address_space(1))) void*)g,
        (__attribute__((address_space(3))) void*)l, 16, 0, 0);
}

// pack two fp32 -> two bf16 (round-half-up) in one uint via v_perm_b32
__device__ __forceinline__ unsigned pack_bf16(float lo, float hi) {
    unsigned a = __builtin_bit_cast(unsigned, lo) + 0x8000u;
    unsigned b = __builtin_bit_cast(unsigned, hi) + 0x8000u;
    return __builtin_amdgcn_perm(b, a, 0x07060302);  // [hi16(b) : hi16(a)]
}

// ---------------- fused pass A: rope tables / convert / 2 transposes ----------------
// R6: inter-dispatch gaps across 7 kernels were significant. All four prep ops
// are independent -> one kernel, grid-partitioned by blockIdx.x.
//   blocks [0,256):        rope tables (2048*32 entries)
//   blocks [256,4352):     x fp32 -> bf16 (4096*1024 elems, 1024/block)
//   blocks [4352,7424):    w_qkv [1024,3072] -> wqkvT [3072,1024] bf16 (32x32 tiles)
//   blocks [7424,8448):    w_out [1024,1024] -> woutT bf16

__global__ __launch_bounds__(256) void prep(const float* __restrict__ x,
                                            const float* __restrict__ w_qkv,
                                            const float* __restrict__ w_out,
                                            unsigned short* __restrict__ xb,
                                            unsigned short* __restrict__ wqkvT,
                                            unsigned short* __restrict__ woutT,
                                            float* __restrict__ cosT,
                                            float* __restrict__ sinT) {
    __shared__ float tile[32][33];
    const int bx = blockIdx.x, tid = threadIdx.x;

    if (bx < 256) {
        // rope tables (libm sincosf: proper range reduction; v_sin_f32 is
        // undefined past +-256 revolutions)
        int i = bx * 256 + tid;                   // 2048*32 = 65536
        int n = i >> 5, f = i & 31;
        float ang = (float)n * exp2f((float)f * -0.4152410118609203f);
        float s, c;
        sincosf(ang, &s, &c);
        cosT[i] = c; sinT[i] = s;
        return;
    }
    if (bx < 4352) {
        int i = ((bx - 256) * 256 + tid) * 4;     // 4096*1024 total
        float4 f = *(const float4*)(x + i);
        ushort4 u;
        u.x = f2bf(f.x); u.y = f2bf(f.y); u.z = f2bf(f.z); u.w = f2bf(f.w);
        *(ushort4*)(xb + i) = u;
        return;
    }
    // transpose branches: in [R,C] fp32 row-major -> out [C,R] bf16 row-major
    const float* in;
    unsigned short* out;
    int R, C, cx, cy;
    if (bx < 7424) {
        int bid = bx - 4352;                      // grid was (96, 32)
        in = w_qkv; out = wqkvT; R = 1024; C = 3072;
        cx = bid % 96; cy = bid / 96;
    } else {
        int bid = bx - 7424;                      // grid was (32, 32)
        in = w_out; out = woutT; R = 1024; C = 1024;
        cx = bid % 32; cy = bid / 32;
    }
    const int c0 = cx * 32, r0 = cy * 32;
    const int tr = tid >> 3;
    const int j4 = (tid & 7) * 4;
    float4 f = *(const float4*)(in + (size_t)(r0 + tr) * C + c0 + j4);
    tile[tr][j4 + 0] = f.x; tile[tr][j4 + 1] = f.y;
    tile[tr][j4 + 2] = f.z; tile[tr][j4 + 3] = f.w;
    __syncthreads();
    ushort4 u;
    u.x = f2bf(tile[j4 + 0][tr]); u.y = f2bf(tile[j4 + 1][tr]);
    u.z = f2bf(tile[j4 + 2][tr]); u.w = f2bf(tile[j4 + 3][tr]);
    *(ushort4*)(out + (size_t)(c0 + tr) * R + r0 + j4) = u;
}

// ---------------- GEMM (A [M,K] bf16) x (Bt [N,K] bf16) ----------------
// Measured-best structure for this problem: m97-style 128^2 tile, 3 blocks/CU,
// global_load_lds width-16 staging, LDS double buffer, ONE barrier per K-iter.
// Multi-block-per-CU overlap hides the barrier drain (m114); both 256^2 8-phase
// ports measured WORSE (60.6us, MfmaUtil 16%: grid 192 < 256 CUs, 1 block/CU
// cannot overlap its own barrier-locked phases).

template <int EPI>
__global__ __launch_bounds__(256, 3) void gemm_bt(const unsigned short* __restrict__ A,
                                                  const unsigned short* __restrict__ Bt,
                                                  int K, int Ncols,
                                                  unsigned short* __restrict__ oq,
                                                  unsigned short* __restrict__ ok,
                                                  unsigned short* __restrict__ ovt,
                                                  float* __restrict__ of,
                                                  const float* __restrict__ cosT,
                                                  const float* __restrict__ sinT) {
    __shared__ unsigned short As[2][128 * 32];
    __shared__ unsigned short Bs[2][128 * 32];
    const int tid = threadIdx.x;
    const int w = tid >> 6, lane = tid & 63, quad = lane >> 4, cc = lane & 15;
    const int wm = w >> 1, wn = w & 1;
    const int m0 = blockIdx.y * 128, n0 = blockIdx.x * 128;

    size_t aoff[2], boff[2];
#pragma unroll
    for (int t = 0; t < 2; t++) {
        int S = w * 128 + t * 64 + lane;
        int row = S >> 2;
        int c = (S & 3) ^ ((row >> 1) & 3);
        aoff[t] = (size_t)(m0 + row) * K + c * 8;
        boff[t] = (size_t)(n0 + row) * K + c * 8;
    }

    // prime buffer 0
#pragma unroll
    for (int t = 0; t < 2; t++) {
        gload16(A + aoff[t], &As[0][(w * 2 + t) * 512]);
        gload16(Bt + boff[t], &Bs[0][(w * 2 + t) * 512]);
    }
    __syncthreads();

    f32x4 acc[4][4] = {};
    const int rpos = (quad ^ ((cc >> 1) & 3)) * 8;   // swizzled chunk offset (shorts)
    const int nkt = K >> 5;

    for (int kt = 0; kt < nkt; kt++) {
        const int pb = kt & 1;
        if (kt < nkt - 1) {
            const int ko = (kt + 1) * 32;
#pragma unroll
            for (int t = 0; t < 2; t++) {
                gload16(A + aoff[t] + ko, &As[pb ^ 1][(w * 2 + t) * 512]);
                gload16(Bt + boff[t] + ko, &Bs[pb ^ 1][(w * 2 + t) * 512]);
            }
        }
        bf16x8 af[4], bf[4];
#pragma unroll
        for (int i = 0; i < 4; i++)
            af[i] = *(const bf16x8*)&As[pb][(wm * 64 + i * 16 + cc) * 32 + rpos];
#pragma unroll
        for (int i = 0; i < 4; i++)
            bf[i] = *(const bf16x8*)&Bs[pb][(wn * 64 + i * 16 + cc) * 32 + rpos];
#pragma unroll
        for (int i = 0; i < 4; i++)
#pragma unroll
            for (int j = 0; j < 4; j++)
                acc[i][j] = MFMA(af[i], bf[j], acc[i][j]);
        __syncthreads();   // drains this iter's DMA + guards buffer swap
    }

    if (EPI == 0) {
        const int e0 = n0 + wn * 64;
        const int which = e0 >> 10;           // 0=q 1=k 2=v
        const int h = (e0 >> 6) & 15;
        if (which < 2) {
            unsigned short* dst = (which == 0) ? oq : ok;
            const float postscale = (which == 0) ? 0.125f : 1.0f;
#pragma unroll
            for (int mf = 0; mf < 4; mf++) {
#pragma unroll
                for (int r = 0; r < 4; r++) {
                    int mg = m0 + wm * 64 + mf * 16 + quad * 4 + r;
                    int nseq = mg & 2047, b = mg >> 11;
                    float vals[4];
#pragma unroll
                    for (int nf = 0; nf < 4; nf++) vals[nf] = acc[mf][nf][r];
                    size_t rowbase = ((size_t)(b * 16 + h) * 2048 + nseq) * 64;
#pragma unroll
                    for (int nf = 0; nf < 4; nf++) {
                        int d = nf * 16 + cc;
                        int f = d & 31;
                        float cs = cosT[nseq * 32 + f];
                        float sn = sinT[nseq * 32 + f];
                        float partner = vals[nf ^ 2];
                        float outv = (vals[nf] * cs +
                                      ((nf < 2) ? -partner : partner) * sn) * postscale;
                        dst[rowbase + d] = f2bf(outv);
                    }
                }
            }
        } else {
#pragma unroll
            for (int mf = 0; mf < 4; mf++) {
                int mg0 = m0 + wm * 64 + mf * 16 + quad * 4;
                int b = mg0 >> 11, nseq = mg0 & 2047;
#pragma unroll
                for (int nf = 0; nf < 4; nf++) {
                    int d = nf * 16 + cc;
                    ushort4 pk;
                    pk.x = f2bf(acc[mf][nf][0]);
                    pk.y = f2bf(acc[mf][nf][1]);
                    pk.z = f2bf(acc[mf][nf][2]);
                    pk.w = f2bf(acc[mf][nf][3]);
                    *(ushort4*)(ovt + ((size_t)(b * 16 + h) * 64 + d) * 2048 + nseq) = pk;
                }
            }
        }
    } else {
#pragma unroll
        for (int mf = 0; mf < 4; mf++)
#pragma unroll
            for (int nf = 0; nf < 4; nf++)
#pragma unroll
                for (int r = 0; r < 4; r++) {
                    int mg = m0 + wm * 64 + mf * 16 + quad * 4 + r;
                    of[(size_t)mg * Ncols + n0 + wn * 64 + nf * 16 + cc] = acc[mf][nf][r];
                }
    }
}

// ---------------- flash attention v8: barrier-free, K/V global->register ----------------
// q,k: [B,H,N,D] bf16 (q pre-scaled by 1/8); vt: [B,H,D,N] bf16; o: [B,N,H*D] bf16
// R7 analysis: every prior attn variant kept cooperative LDS staging + a per-iter
// block-wide barrier, phase-locking all 16 waves/CU so QK/softmax/PV bursts SUM
// (~4050cy/iter, no pipe >46%). This version deletes staging and the in-loop
// barrier entirely: each wave loads its 8 K-frags and 8 V-frags DIRECTLY
// global->register -- the same 16B chunks it used to ds_read (LDS swizzle algebra
// cancels: chunk kc*4+quad of row nf*16+cc). K/V tiles are L2/L1-resident
// (FETCH 12.3MB total; 2MB/XCD working set; 8 waves/block share each 16KB tile
// via L1). Waves run their 32 iterations fully independently: 4 waves/SIMD
// self-schedule, TLP replaces barrier-pipelining. LDS 19KB (ps+rsb only, both
// wave-private -> no barrier until epilogue). VGPR bounded by loading K/V frags
// 4-at-a-time per kc; __launch_bounds__(512,4) caps at 128.

__global__ __launch_bounds__(512, 4) void attn(const unsigned short* __restrict__ q,
                                               const unsigned short* __restrict__ k,
                                               const unsigned short* __restrict__ vt,
                                               unsigned short* __restrict__ o) {
    __shared__ unsigned short ps[128 * 72];
    __shared__ float rsb[128];
    const int tid = threadIdx.x;
    const int w = tid >> 6, lane = tid & 63, quad = lane >> 4, cc = lane & 15;
    const int bh = blockIdx.x & 31, qt = blockIdx.x >> 5;

    // Q fragments -> registers (A-layout: lane(quad,cc) holds Q[m=cc][k=quad*8+j])
    const unsigned short* qg = q + ((size_t)bh * 2048 + qt * 128 + w * 16) * 64;
    bf16x8 aq[2];
#pragma unroll
    for (int kc = 0; kc < 2; kc++)
        aq[kc] = *(const bf16x8*)(qg + cc * 64 + kc * 32 + quad * 8);

    // per-lane K/V fragment base pointers (tile 0); advance per iteration.
    // K frag (nf,kc): krb + nf*1024 + kc*32   (row nf*16+cc, chunk kc*4+quad)
    // V frag (df,kc): vrb + df*32768 + kc*32  (row df*16+cc of vt, stride 2048)
    const unsigned short* krb = k + (size_t)bh * 2048 * 64 + cc * 64 + quad * 8;
    const unsigned short* vrb = vt + (size_t)bh * 64 * 2048 + cc * 2048 + quad * 8;

    f32x4 oacc[4] = {};
    float rs = 0.f;

    for (int kt = 0; kt < 32; kt++) {
        // S^T = MFMA(K-rows, Q-rows): s2[nf] reg r = S[m=cc][n=nf*16+quad*4+r]
        f32x4 s2[4] = {};
#pragma unroll
        for (int kc = 0; kc < 2; kc++) {
            bf16x8 bk0 = *(const bf16x8*)(krb + 0 * 1024 + kc * 32);
            bf16x8 bk1 = *(const bf16x8*)(krb + 1 * 1024 + kc * 32);
            bf16x8 bk2 = *(const bf16x8*)(krb + 2 * 1024 + kc * 32);
            bf16x8 bk3 = *(const bf16x8*)(krb + 3 * 1024 + kc * 32);
            __builtin_amdgcn_s_setprio(1);
            s2[0] = MFMA(bk0, aq[kc], s2[0]);
            s2[1] = MFMA(bk1, aq[kc], s2[1]);
            s2[2] = MFMA(bk2, aq[kc], s2[2]);
            s2[3] = MFMA(bk3, aq[kc], s2[3]);
            __builtin_amdgcn_s_setprio(0);
        }
        krb += 4096;

        // p = exp(s - 8); in-lane row-sum; pack 4 consecutive-n p's -> one b64 write
#pragma unroll
        for (int nf = 0; nf < 4; nf++) {
            float p0 = __builtin_amdgcn_exp2f(
                __builtin_fmaf(s2[nf][0], 1.44269504f, -11.54156036f));
            float p1 = __builtin_amdgcn_exp2f(
                __builtin_fmaf(s2[nf][1], 1.44269504f, -11.54156036f));
            float p2 = __builtin_amdgcn_exp2f(
                __builtin_fmaf(s2[nf][2], 1.44269504f, -11.54156036f));
            float p3 = __builtin_amdgcn_exp2f(
                __builtin_fmaf(s2[nf][3], 1.44269504f, -11.54156036f));
            rs += (p0 + p1) + (p2 + p3);
            uint2 pk;
            pk.x = pack_bf16(p0, p1);
            pk.y = pack_bf16(p2, p3);
            *(uint2*)&ps[(w * 16 + cc) * 72 + nf * 16 + quad * 4] = pk;
        }

        // O += P V   (ps rows wave-private: lgkmcnt ordering suffices, no barrier)
#pragma unroll
        for (int kc = 0; kc < 2; kc++) {
            bf16x8 ap = *(const bf16x8*)&ps[(w * 16 + cc) * 72 + kc * 32 + quad * 8];
            bf16x8 bv0 = *(const bf16x8*)(vrb + 0 * 32768 + kc * 32);
            bf16x8 bv1 = *(const bf16x8*)(vrb + 1 * 32768 + kc * 32);
            bf16x8 bv2 = *(const bf16x8*)(vrb + 2 * 32768 + kc * 32);
            bf16x8 bv3 = *(const bf16x8*)(vrb + 3 * 32768 + kc * 32);
            __builtin_amdgcn_s_setprio(1);
            oacc[0] = MFMA(ap, bv0, oacc[0]);
            oacc[1] = MFMA(ap, bv1, oacc[1]);
            oacc[2] = MFMA(ap, bv2, oacc[2]);
            oacc[3] = MFMA(ap, bv3, oacc[3]);
            __builtin_amdgcn_s_setprio(0);
        }
        vrb += 64;
    }

    // row-sum: reduce over the 4 quads holding row m=cc, then stage for epilogue
    rs += __shfl_xor(rs, 16, 64);
    rs += __shfl_xor(rs, 32, 64);
    if (quad == 0) rsb[w * 16 + cc] = rs;
    // wave-private rsb region: per-wave LDS program order suffices, no barrier

    {
        f32x4 rv = *(const f32x4*)&rsb[w * 16 + quad * 4];
        f32x4 inv;
#pragma unroll
        for (int r = 0; r < 4; r++) inv[r] = 1.0f / rv[r];
#pragma unroll
        for (int r = 0; r < 4; r++)
#pragma unroll
            for (int df = 0; df < 4; df++)
                ps[(w * 16 + quad * 4 + r) * 72 + df * 16 + cc] =
                    f2bf(oacc[df][r] * inv[r]);
    }
    __syncthreads();
    {
        const int b = bh >> 4, h = bh & 15;
        int row2 = tid >> 2, seg = tid & 3;    // 128 rows x 4 segments of 16 shorts
        unsigned short* og =
            o + ((size_t)(b * 2048 + qt * 128 + row2)) * 1024 + h * 64 + seg * 16;
#pragma unroll
        for (int j = 0; j < 2; j++)
            *(uint4*)(og + j * 8) = *(const uint4*)&ps[row2 * 72 + seg * 16 + j * 8];
    }
}

// ---------------- launcher ----------------

extern "C" void kernel_launch(void* const* d_in, const int* in_sizes, int n_in,
                              void* d_out, int out_size, void* d_ws, size_t ws_size,
                              hipStream_t stream) {
    const float* x = (const float*)d_in[0];
    const float* w_qkv = (const float*)d_in[1];
    const float* w_out = (const float*)d_in[2];
    float* out = (float*)d_out;

    unsigned short* xb    = (unsigned short*)d_ws;        // 4096*1024
    unsigned short* wqkvT = xb + 4096 * 1024;             // 3072*1024
    unsigned short* woutT = wqkvT + 3072 * 1024;          // 1024*1024
    unsigned short* qb    = woutT + 1024 * 1024;          // 2*16*2048*64
    unsigned short* kb    = qb + 2 * 16 * 2048 * 64;
    unsigned short* vtb   = kb + 2 * 16 * 2048 * 64;
    unsigned short* ob    = vtb + 2 * 16 * 2048 * 64;     // 4096*1024
    float* cosT = (float*)(ob + 4096 * 1024);             // 2048*32 fp32
    float* sinT = cosT + 2048 * 32;

    prep<<<8448, 256, 0, stream>>>(x, w_qkv, w_out, xb, wqkvT, woutT, cosT, sinT);
    gemm_bt<0><<<dim3(24, 32), 256, 0, stream>>>(xb, wqkvT, 1024, 3072,
                                                 qb, kb, vtb, nullptr, cosT, sinT);
    attn<<<512, 512, 0, stream>>>(qb, kb, vtb, ob);
    gemm_bt<1><<<dim3(8, 32), 256, 0, stream>>>(ob, woutT, 1024, 1024,
                                                nullptr, nullptr, nullptr, out,
                                                nullptr, nullptr);
}

// Round 9
// 177.521 us; speedup vs baseline: 2.0331x; 2.0331x over previous
//
#include <hip/hip_runtime.h>

typedef __attribute__((ext_vector_type(8))) short bf16x8;
typedef __attribute__((ext_vector_type(4))) float f32x4;

#define MFMA(a, b, c) __builtin_amdgcn_mfma_f32_16x16x32_bf16(a, b, c, 0, 0, 0)

__device__ __forceinline__ unsigned short f2bf(float f) {
    unsigned u = __builtin_bit_cast(unsigned, f);
    u += 0x7fffu + ((u >> 16) & 1u);
    return (unsigned short)(u >> 16);
}

// async global->LDS DMA, 16B per lane; hardware writes lane i's data at
// (wave-uniform) lds base + i*16B. gptr is per-lane.
__device__ __forceinline__ void gload16(const unsigned short* g, unsigned short* l) {
    __builtin_amdgcn_global_load_lds(
        (const __attribute__((address_space(1))) void*)g,
        (__attribute__((address_space(3))) void*)l, 16, 0, 0);
}

// pack two fp32 -> two bf16 (round-half-up) in one uint via v_perm_b32
__device__ __forceinline__ unsigned pack_bf16(float lo, float hi) {
    unsigned a = __builtin_bit_cast(unsigned, lo) + 0x8000u;
    unsigned b = __builtin_bit_cast(unsigned, hi) + 0x8000u;
    return __builtin_amdgcn_perm(b, a, 0x07060302);  // [hi16(b) : hi16(a)]
}

// ---------------- fused pass A: rope tables / convert / 2 transposes ----------------
// R7: fusing 4 independent prep launches into one grid-partitioned kernel was
// worth ~7us of inter-dispatch gap.
//   blocks [0,256):        rope tables (2048*32 entries)
//   blocks [256,4352):     x fp32 -> bf16 (4096*1024 elems, 1024/block)
//   blocks [4352,7424):    w_qkv [1024,3072] -> wqkvT [3072,1024] bf16 (32x32 tiles)
//   blocks [7424,8448):    w_out [1024,1024] -> woutT bf16

__global__ __launch_bounds__(256) void prep(const float* __restrict__ x,
                                            const float* __restrict__ w_qkv,
                                            const float* __restrict__ w_out,
                                            unsigned short* __restrict__ xb,
                                            unsigned short* __restrict__ wqkvT,
                                            unsigned short* __restrict__ woutT,
                                            float* __restrict__ cosT,
                                            float* __restrict__ sinT) {
    __shared__ float tile[32][33];
    const int bx = blockIdx.x, tid = threadIdx.x;

    if (bx < 256) {
        // rope tables (libm sincosf: proper range reduction; v_sin_f32 is
        // undefined past +-256 revolutions)
        int i = bx * 256 + tid;                   // 2048*32 = 65536
        int n = i >> 5, f = i & 31;
        float ang = (float)n * exp2f((float)f * -0.4152410118609203f);
        float s, c;
        sincosf(ang, &s, &c);
        cosT[i] = c; sinT[i] = s;
        return;
    }
    if (bx < 4352) {
        int i = ((bx - 256) * 256 + tid) * 4;     // 4096*1024 total
        float4 f = *(const float4*)(x + i);
        ushort4 u;
        u.x = f2bf(f.x); u.y = f2bf(f.y); u.z = f2bf(f.z); u.w = f2bf(f.w);
        *(ushort4*)(xb + i) = u;
        return;
    }
    // transpose branches: in [R,C] fp32 row-major -> out [C,R] bf16 row-major
    const float* in;
    unsigned short* out;
    int R, C, cx, cy;
    if (bx < 7424) {
        int bid = bx - 4352;                      // grid was (96, 32)
        in = w_qkv; out = wqkvT; R = 1024; C = 3072;
        cx = bid % 96; cy = bid / 96;
    } else {
        int bid = bx - 7424;                      // grid was (32, 32)
        in = w_out; out = woutT; R = 1024; C = 1024;
        cx = bid % 32; cy = bid / 32;
    }
    const int c0 = cx * 32, r0 = cy * 32;
    const int tr = tid >> 3;
    const int j4 = (tid & 7) * 4;
    float4 f = *(const float4*)(in + (size_t)(r0 + tr) * C + c0 + j4);
    tile[tr][j4 + 0] = f.x; tile[tr][j4 + 1] = f.y;
    tile[tr][j4 + 2] = f.z; tile[tr][j4 + 3] = f.w;
    __syncthreads();
    ushort4 u;
    u.x = f2bf(tile[j4 + 0][tr]); u.y = f2bf(tile[j4 + 1][tr]);
    u.z = f2bf(tile[j4 + 2][tr]); u.w = f2bf(tile[j4 + 3][tr]);
    *(ushort4*)(out + (size_t)(c0 + tr) * R + r0 + j4) = u;
}

// ---------------- QKV GEMM (A [M,K] bf16) x (Bt [N,K] bf16) ----------------
// Measured-best structure for this problem: m97-style 128^2 tile, 768 blocks =
// 3 blocks/CU, global_load_lds width-16 staging, LDS double buffer, ONE barrier
// per K-iter. Multi-block-per-CU overlap hides the barrier drain (m114); both
// 256^2 8-phase ports measured WORSE (60.6us, MfmaUtil 16%: grid 192 < 256 CUs,
// 1 block/CU cannot overlap its own barrier-locked phases).

__global__ __launch_bounds__(256, 3) void gemm_qkv(const unsigned short* __restrict__ A,
                                                   const unsigned short* __restrict__ Bt,
                                                   unsigned short* __restrict__ oq,
                                                   unsigned short* __restrict__ ok,
                                                   unsigned short* __restrict__ ovt,
                                                   const float* __restrict__ cosT,
                                                   const float* __restrict__ sinT) {
    __shared__ unsigned short As[2][128 * 32];
    __shared__ unsigned short Bs[2][128 * 32];
    const int K = 1024;
    const int tid = threadIdx.x;
    const int w = tid >> 6, lane = tid & 63, quad = lane >> 4, cc = lane & 15;
    const int wm = w >> 1, wn = w & 1;
    const int m0 = blockIdx.y * 128, n0 = blockIdx.x * 128;

    size_t aoff[2], boff[2];
#pragma unroll
    for (int t = 0; t < 2; t++) {
        int S = w * 128 + t * 64 + lane;
        int row = S >> 2;
        int c = (S & 3) ^ ((row >> 1) & 3);
        aoff[t] = (size_t)(m0 + row) * K + c * 8;
        boff[t] = (size_t)(n0 + row) * K + c * 8;
    }

    // prime buffer 0
#pragma unroll
    for (int t = 0; t < 2; t++) {
        gload16(A + aoff[t], &As[0][(w * 2 + t) * 512]);
        gload16(Bt + boff[t], &Bs[0][(w * 2 + t) * 512]);
    }
    __syncthreads();

    f32x4 acc[4][4] = {};
    const int rpos = (quad ^ ((cc >> 1) & 3)) * 8;   // swizzled chunk offset (shorts)

    for (int kt = 0; kt < 32; kt++) {
        const int pb = kt & 1;
        if (kt < 31) {
            const int ko = (kt + 1) * 32;
#pragma unroll
            for (int t = 0; t < 2; t++) {
                gload16(A + aoff[t] + ko, &As[pb ^ 1][(w * 2 + t) * 512]);
                gload16(Bt + boff[t] + ko, &Bs[pb ^ 1][(w * 2 + t) * 512]);
            }
        }
        bf16x8 af[4], bf[4];
#pragma unroll
        for (int i = 0; i < 4; i++)
            af[i] = *(const bf16x8*)&As[pb][(wm * 64 + i * 16 + cc) * 32 + rpos];
#pragma unroll
        for (int i = 0; i < 4; i++)
            bf[i] = *(const bf16x8*)&Bs[pb][(wn * 64 + i * 16 + cc) * 32 + rpos];
#pragma unroll
        for (int i = 0; i < 4; i++)
#pragma unroll
            for (int j = 0; j < 4; j++)
                acc[i][j] = MFMA(af[i], bf[j], acc[i][j]);
        __syncthreads();   // drains this iter's DMA + guards buffer swap
    }

    // ---- epilogue: q/k get RoPE + scale; v written transposed ----
    const int e0 = n0 + wn * 64;
    const int which = e0 >> 10;           // 0=q 1=k 2=v
    const int h = (e0 >> 6) & 15;
    if (which < 2) {
        unsigned short* dst = (which == 0) ? oq : ok;
        const float postscale = (which == 0) ? 0.125f : 1.0f;
#pragma unroll
        for (int mf = 0; mf < 4; mf++) {
#pragma unroll
            for (int r = 0; r < 4; r++) {
                int mg = m0 + wm * 64 + mf * 16 + quad * 4 + r;
                int nseq = mg & 2047, b = mg >> 11;
                float vals[4];
#pragma unroll
                for (int nf = 0; nf < 4; nf++) vals[nf] = acc[mf][nf][r];
                size_t rowbase = ((size_t)(b * 16 + h) * 2048 + nseq) * 64;
#pragma unroll
                for (int nf = 0; nf < 4; nf++) {
                    int d = nf * 16 + cc;
                    int f = d & 31;
                    float cs = cosT[nseq * 32 + f];
                    float sn = sinT[nseq * 32 + f];
                    float partner = vals[nf ^ 2];
                    float outv = (vals[nf] * cs +
                                  ((nf < 2) ? -partner : partner) * sn) * postscale;
                    dst[rowbase + d] = f2bf(outv);
                }
            }
        }
    } else {
#pragma unroll
        for (int mf = 0; mf < 4; mf++) {
            int mg0 = m0 + wm * 64 + mf * 16 + quad * 4;
            int b = mg0 >> 11, nseq = mg0 & 2047;
#pragma unroll
            for (int nf = 0; nf < 4; nf++) {
                int d = nf * 16 + cc;
                ushort4 pk;
                pk.x = f2bf(acc[mf][nf][0]);
                pk.y = f2bf(acc[mf][nf][1]);
                pk.z = f2bf(acc[mf][nf][2]);
                pk.w = f2bf(acc[mf][nf][3]);
                *(ushort4*)(ovt + ((size_t)(b * 16 + h) * 64 + d) * 2048 + nseq) = pk;
            }
        }
    }
}

// ---------------- output GEMM: 128x64 tile for 2 blocks/CU (R8) ----------------
// ob [4096,1024] bf16 x woutT [1024,1024] bf16 -> out [4096,1024] fp32.
// R8 analysis: the 128^2 version ran grid (8,32)=256 blocks = 1 block/CU --
// the configuration R5/R6 proved pathological for the barrier-locked m97
// structure (no co-resident block to overlap the per-iter drain; m114 overlap
// is the whole trick). Tile 128Mx64N -> grid (16,32) = 512 blocks = 2/CU.
// LDS 24KB (A 2x8KB, B 2x4KB). A staged 2 slots/thread, B 1 slot/thread;
// same chunk-XOR swizzle; per wave-iter 4 af + 2 bf ds_reads, 8 MFMA.

__global__ __launch_bounds__(256, 4) void gemm_out(const unsigned short* __restrict__ A,
                                                   const unsigned short* __restrict__ Bt,
                                                   float* __restrict__ of) {
    __shared__ unsigned short As[2][128 * 32];
    __shared__ unsigned short Bs[2][64 * 32];
    const int K = 1024, Ncols = 1024;
    const int tid = threadIdx.x;
    const int w = tid >> 6, lane = tid & 63, quad = lane >> 4, cc = lane & 15;
    const int wm = w >> 1, wn = w & 1;
    const int m0 = blockIdx.y * 128, n0 = blockIdx.x * 64;

    size_t aoff[2], boff;
#pragma unroll
    for (int t = 0; t < 2; t++) {
        int S = w * 128 + t * 64 + lane;
        int row = S >> 2;
        int c = (S & 3) ^ ((row >> 1) & 3);
        aoff[t] = (size_t)(m0 + row) * K + c * 8;
    }
    {
        int S = w * 64 + lane;          // 256 slots cover the 64x32 B tile
        int row = S >> 2;
        int c = (S & 3) ^ ((row >> 1) & 3);
        boff = (size_t)(n0 + row) * K + c * 8;
    }

    // prime buffer 0
#pragma unroll
    for (int t = 0; t < 2; t++)
        gload16(A + aoff[t], &As[0][(w * 2 + t) * 512]);
    gload16(Bt + boff, &Bs[0][w * 512]);
    __syncthreads();

    f32x4 acc[4][2] = {};
    const int rpos = (quad ^ ((cc >> 1) & 3)) * 8;

    for (int kt = 0; kt < 32; kt++) {
        const int pb = kt & 1;
        if (kt < 31) {
            const int ko = (kt + 1) * 32;
#pragma unroll
            for (int t = 0; t < 2; t++)
                gload16(A + aoff[t] + ko, &As[pb ^ 1][(w * 2 + t) * 512]);
            gload16(Bt + boff + ko, &Bs[pb ^ 1][w * 512]);
        }
        bf16x8 af[4], bf[2];
#pragma unroll
        for (int i = 0; i < 4; i++)
            af[i] = *(const bf16x8*)&As[pb][(wm * 64 + i * 16 + cc) * 32 + rpos];
#pragma unroll
        for (int j = 0; j < 2; j++)
            bf[j] = *(const bf16x8*)&Bs[pb][(wn * 32 + j * 16 + cc) * 32 + rpos];
#pragma unroll
        for (int i = 0; i < 4; i++)
#pragma unroll
            for (int j = 0; j < 2; j++)
                acc[i][j] = MFMA(af[i], bf[j], acc[i][j]);
        __syncthreads();
    }

#pragma unroll
    for (int mf = 0; mf < 4; mf++)
#pragma unroll
        for (int nf = 0; nf < 2; nf++)
#pragma unroll
            for (int r = 0; r < 4; r++) {
                int mg = m0 + wm * 64 + mf * 16 + quad * 4 + r;
                of[(size_t)mg * Ncols + n0 + wn * 32 + nf * 16 + cc] = acc[mf][nf][r];
            }
}

// ---------------- flash attention v4 (FROZEN: best of 6 variants, 54.2us) ----------------
// q,k: [B,H,N,D] bf16 (q pre-scaled by 1/8); vt: [B,H,D,N] bf16; o: [B,N,H*D] bf16
// 512 threads: 8 waves x 16 q-rows; 2 blocks/CU -> 4 waves/SIMD. S^T orientation:
// S^T = MFMA(bk, aq); P staged via wave-private ps rows; per-iter __syncthreads
// drains DMA + guards double buffer. Tried and rejected: P-in-register permlane
// (R2 flat), counted-vmcnt 3-deep (R3 -2us), kv-gang 32-rows/wave (R4 -4us),
// barrier-free global->reg (R8 -183us: per-lane scattered loads = serial L2
// latency; the cooperative LDS-DMA + barrier structure IS the prefetch engine).

__global__ __launch_bounds__(512, 4) void attn(const unsigned short* __restrict__ q,
                                               const unsigned short* __restrict__ k,
                                               const unsigned short* __restrict__ vt,
                                               unsigned short* __restrict__ o) {
    __shared__ unsigned short ks[2][64 * 64];
    __shared__ unsigned short vs[2][64 * 64];
    __shared__ unsigned short ps[128 * 72];
    __shared__ float rsb[128];
    const int tid = threadIdx.x;
    const int w = tid >> 6, lane = tid & 63, quad = lane >> 4, cc = lane & 15;
    const int bh = blockIdx.x & 31, qt = blockIdx.x >> 5;

    const unsigned short* qg = q + ((size_t)bh * 2048 + qt * 128 + w * 16) * 64;
    bf16x8 aq[2];
#pragma unroll
    for (int kc = 0; kc < 2; kc++)
        aq[kc] = *(const bf16x8*)(qg + cc * 64 + kc * 32 + quad * 8);

    const int S = w * 64 + lane;
    const int row = S >> 3;
    const int c = (S & 7) ^ (row & 7);
    const int koff = row * 64 + c * 8;
    const int voff = row * 2048 + c * 8;

    const unsigned short* kg0 = k + (size_t)bh * 2048 * 64;
    const unsigned short* vg0 = vt + (size_t)bh * 64 * 2048;

    gload16(kg0 + koff, &ks[0][w * 512]);
    gload16(vg0 + voff, &vs[0][w * 512]);
    __syncthreads();

    f32x4 oacc[4] = {};
    float rs = 0.f;

    for (int kt = 0; kt < 32; kt++) {
        const int pb = kt & 1;
        if (kt < 31) {
            const unsigned short* kb = kg0 + (kt + 1) * 4096;
            const unsigned short* vb = vg0 + (kt + 1) * 64;
            gload16(kb + koff, &ks[pb ^ 1][w * 512]);
            gload16(vb + voff, &vs[pb ^ 1][w * 512]);
        }

        f32x4 s2[4] = {};
        __builtin_amdgcn_s_setprio(1);
#pragma unroll
        for (int kc = 0; kc < 2; kc++) {
#pragma unroll
            for (int nf = 0; nf < 4; nf++) {
                bf16x8 bk = *(const bf16x8*)&ks[pb][(nf * 16 + cc) * 64 +
                                                    ((kc * 4 + quad) ^ (cc & 7)) * 8];
                s2[nf] = MFMA(bk, aq[kc], s2[nf]);
            }
        }
        __builtin_amdgcn_s_setprio(0);

#pragma unroll
        for (int nf = 0; nf < 4; nf++) {
            float p0 = __builtin_amdgcn_exp2f(
                __builtin_fmaf(s2[nf][0], 1.44269504f, -11.54156036f));
            float p1 = __builtin_amdgcn_exp2f(
                __builtin_fmaf(s2[nf][1], 1.44269504f, -11.54156036f));
            float p2 = __builtin_amdgcn_exp2f(
                __builtin_fmaf(s2[nf][2], 1.44269504f, -11.54156036f));
            float p3 = __builtin_amdgcn_exp2f(
                __builtin_fmaf(s2[nf][3], 1.44269504f, -11.54156036f));
            rs += (p0 + p1) + (p2 + p3);
            uint2 pk;
            pk.x = pack_bf16(p0, p1);
            pk.y = pack_bf16(p2, p3);
            *(uint2*)&ps[(w * 16 + cc) * 72 + nf * 16 + quad * 4] = pk;
        }

#pragma unroll
        for (int kc = 0; kc < 2; kc++) {
            bf16x8 ap = *(const bf16x8*)&ps[(w * 16 + cc) * 72 + kc * 32 + quad * 8];
            __builtin_amdgcn_s_setprio(1);
#pragma unroll
            for (int df = 0; df < 4; df++) {
                bf16x8 bv = *(const bf16x8*)&vs[pb][(df * 16 + cc) * 64 +
                                                    ((kc * 4 + quad) ^ (cc & 7)) * 8];
                oacc[df] = MFMA(ap, bv, oacc[df]);
            }
            __builtin_amdgcn_s_setprio(0);
        }

        __syncthreads();
    }

    rs += __shfl_xor(rs, 16, 64);
    rs += __shfl_xor(rs, 32, 64);
    if (quad == 0) rsb[w * 16 + cc] = rs;

    {
        f32x4 rv = *(const f32x4*)&rsb[w * 16 + quad * 4];
        f32x4 inv;
#pragma unroll
        for (int r = 0; r < 4; r++) inv[r] = 1.0f / rv[r];
#pragma unroll
        for (int r = 0; r < 4; r++)
#pragma unroll
            for (int df = 0; df < 4; df++)
                ps[(w * 16 + quad * 4 + r) * 72 + df * 16 + cc] =
                    f2bf(oacc[df][r] * inv[r]);
    }
    __syncthreads();
    {
        const int b = bh >> 4, h = bh & 15;
        int row2 = tid >> 2, seg = tid & 3;
        unsigned short* og =
            o + ((size_t)(b * 2048 + qt * 128 + row2)) * 1024 + h * 64 + seg * 16;
#pragma unroll
        for (int j = 0; j < 2; j++)
            *(uint4*)(og + j * 8) = *(const uint4*)&ps[row2 * 72 + seg * 16 + j * 8];
    }
}

// ---------------- launcher ----------------

extern "C" void kernel_launch(void* const* d_in, const int* in_sizes, int n_in,
                              void* d_out, int out_size, void* d_ws, size_t ws_size,
                              hipStream_t stream) {
    const float* x = (const float*)d_in[0];
    const float* w_qkv = (const float*)d_in[1];
    const float* w_out = (const float*)d_in[2];
    float* out = (float*)d_out;

    unsigned short* xb    = (unsigned short*)d_ws;        // 4096*1024
    unsigned short* wqkvT = xb + 4096 * 1024;             // 3072*1024
    unsigned short* woutT = wqkvT + 3072 * 1024;          // 1024*1024
    unsigned short* qb    = woutT + 1024 * 1024;          // 2*16*2048*64
    unsigned short* kb    = qb + 2 * 16 * 2048 * 64;
    unsigned short* vtb   = kb + 2 * 16 * 2048 * 64;
    unsigned short* ob    = vtb + 2 * 16 * 2048 * 64;     // 4096*1024
    float* cosT = (float*)(ob + 4096 * 1024);             // 2048*32 fp32
    float* sinT = cosT + 2048 * 32;

    prep<<<8448, 256, 0, stream>>>(x, w_qkv, w_out, xb, wqkvT, woutT, cosT, sinT);
    gemm_qkv<<<dim3(24, 32), 256, 0, stream>>>(xb, wqkvT, qb, kb, vtb, cosT, sinT);
    attn<<<512, 512, 0, stream>>>(qb, kb, vtb, ob);
    gemm_out<<<dim3(16, 32), 256, 0, stream>>>(ob, woutT, out);
}